// Round 6
// baseline (105.231 us; speedup 1.0000x reference)
//
#include <hip/hip_runtime.h>

typedef unsigned long long u64;

#define S_LEN 2048
#define BATCH 8
#define NTOK 64
#define DMODEL 648
#define NBLK 32   // 32 blocks of 64 positions

// Workspace layout (u64 units):
//   P  [BATCH][2048]     @ 0      : bit jj of P[b][w*64+t]        = (src[64w+jj]   == t)
//   SH [BATCH][4][2048]  @ 16384  : bit jj of SH[b][d-1][w*64+t]  = (src[64w+jj-d] == t)
//   sT [BATCH][S_LEN]    @ 81920  : transposed src column (int)
// Total 768 KB -> L2-resident for the compute kernel.

// ---------------------------------------------------------------------------
// Build: one 64-thread wave per (block w, batch b). Lane j holds token at
// position 64w+j; per-token masks via __ballot; lane t keeps token-t masks.
// Four pre-shifted tables (shift d=1..4, cross-block carry from prev block).
// ---------------------------------------------------------------------------
__global__ __launch_bounds__(64) void build_kernel(const int* __restrict__ src,
                                                   u64* __restrict__ P,
                                                   u64* __restrict__ SH,
                                                   int* __restrict__ sT) {
    const int w = blockIdx.x, b = blockIdx.y;
    const int lane = threadIdx.x;
    const int p = (w << 6) + lane;
    const int tok  = src[p * BATCH + b];
    const int tokp = (w > 0) ? src[(p - 64) * BATCH + b] : -1;  // prev block
    u64 m_sel = 0, mp_sel = 0;
    #pragma unroll 8
    for (int t = 0; t < NTOK; ++t) {
        const u64 m  = __ballot(tok == t);
        const u64 mp = __ballot(tokp == t);
        if (lane == t) { m_sel = m; mp_sel = mp; }
    }
    const int idx = (w << 6) + lane;        // lane == token slot
    P[b * 2048 + idx] = m_sel;
    u64* S = SH + (size_t)b * 8192;
    S[0 * 2048 + idx] = (m_sel << 1) | (mp_sel >> 63);
    S[1 * 2048 + idx] = (m_sel << 2) | (mp_sel >> 62);
    S[2 * 2048 + idx] = (m_sel << 3) | (mp_sel >> 61);
    S[3 * 2048 + idx] = (m_sel << 4) | (mp_sel >> 60);
    sT[b * S_LEN + p] = tok;
}

// ---------------------------------------------------------------------------
// Compute: ZERO LDS -> 8 WG/CU, 32 waves/CU. Each wave owns q-pair {2k,2k+1}
// plus mirror pair {2046-2k, 2047-2k}  (k = blockIdx.x*4+wv in 0..511 per b)
// -> every wave does ~32 block-iterations (balanced). Lane = token id.
// Branchless chain per q, all rows read as wave-uniform global broadcast
// loads (L2-hit, ~8B each):
//   A1 = S1[w][s[q]] & pv  (pv = P[w][lane], coalesced)
//   A2 = A1 & S2[w][s[q-1]], A3 = A2 & S3[w][s[q-2]], A4 = A3 & S4[w][s[q-3]]
//   h_i[lane] += popc(A_i);  c_i = wave-sum h_i (packed shfl reduce).
// ---------------------------------------------------------------------------
__global__ __launch_bounds__(256) void compute_kernel(const u64* __restrict__ P,
                                                      const u64* __restrict__ SH,
                                                      const int* __restrict__ sT,
                                                      float* __restrict__ out) {
    const int b = blockIdx.y;
    const int tid = threadIdx.x;
    const int lane = tid & 63;
    const int wv = tid >> 6;

    const int k = blockIdx.x * 4 + wv;   // 0..511 per b

    const int* s = sT + b * S_LEN;
    const u64* Pb = P + (size_t)b * 2048;
    const u64* S1 = SH + (size_t)b * 8192;
    const u64* S2 = S1 + 2048;
    const u64* S3 = S1 + 4096;
    const u64* S4 = S1 + 6144;

    #pragma unroll 1
    for (int g = 0; g < 2; ++g) {
        const int pairid = g ? (1023 - k) : k;
        const int q0 = pairid << 1;      // q0 even; q0, q0+1 share a block

        int tk[6];
        #pragma unroll
        for (int i = 0; i < 6; ++i) {
            const int idx = q0 - 4 + i;
            tk[i] = (idx >= 0) ? s[idx] : 0;   // clamp: provably-dead rows
        }

        int h1[2] = {}, h2[2] = {}, h3[2] = {}, h4[2] = {};
        int cuP[2];
        int cuF = 0;
        const int wq = q0 >> 6, rem0 = q0 & 63;

        for (int w = 0; w < wq; ++w) {
            const int wb = w << 6;
            const u64 pv = Pb[wb + lane];
            cuF += __popcll(pv);
            #pragma unroll
            for (int r = 0; r < 2; ++r) {
                const u64 A1 = S1[wb + tk[4 + r]] & pv;
                const u64 A2 = A1 & S2[wb + tk[3 + r]];
                const u64 A3 = A2 & S3[wb + tk[2 + r]];
                const u64 A4 = A3 & S4[wb + tk[1 + r]];
                h1[r] += __popcll(A1);
                h2[r] += __popcll(A2);
                h3[r] += __popcll(A3);
                h4[r] += __popcll(A4);
            }
        }

        {   // partial block w = wq: j-bits jj < rem0 + r
            const int wb = wq << 6;
            const u64 pv = Pb[wb + lane];
            #pragma unroll
            for (int r = 0; r < 2; ++r) {
                const int rem = rem0 + r;                  // <= 63
                const u64 valid = (1ull << rem) - 1ull;    // rem==0 -> 0
                const u64 pvv = pv & valid;
                cuP[r] = cuF + __popcll(pvv);
                const u64 A1 = S1[wb + tk[4 + r]] & pvv;
                const u64 A2 = A1 & S2[wb + tk[3 + r]];
                const u64 A3 = A2 & S3[wb + tk[2 + r]];
                const u64 A4 = A3 & S4[wb + tk[1 + r]];
                h1[r] += __popcll(A1);
                h2[r] += __popcll(A2);
                h3[r] += __popcll(A3);
                h4[r] += __popcll(A4);
            }
        }

        // c_i = wave-sum of h_i (packed 2x16-bit, 2 independent chains)
        #pragma unroll
        for (int r = 0; r < 2; ++r) {
            const int q = q0 + r;
            int p01 = h1[r] | (h2[r] << 16);
            int p23 = h3[r] | (h4[r] << 16);
            #pragma unroll
            for (int sft = 1; sft < 64; sft <<= 1) {
                p01 += __shfl_xor(p01, sft);
                p23 += __shfl_xor(p23, sft);
            }
            const int c1 = p01 & 0xffff, c2 = p01 >> 16;
            const int c3 = p23 & 0xffff, c4 = p23 >> 16;

            float* op = out + ((size_t)q * BATCH + b) * DMODEL;
            #pragma unroll
            for (int m = 0; m <= 4; ++m) {   // one-hot blocks, sentinel -> 0
                const bool sent = (q - m) < 0;
                op[m * 64 + lane] = (!sent && lane == tk[4 + r - m]) ? 1.f : 0.f;
            }
            op[320 + lane] = (float)h1[r] / (float)(c1 ? c1 : 1);
            op[384 + lane] = (float)h2[r] / (float)(c2 ? c2 : 1);
            op[448 + lane] = (float)h3[r] / (float)(c3 ? c3 : 1);
            op[512 + lane] = (float)h4[r] / (float)(c4 ? c4 : 1);
            op[576 + lane] = (float)cuP[r] / (float)(q ? q : 1);
            if (lane < 8) {
                float v = 0.f;
                if (lane == 0) v = (float)c1;
                else if (lane == 1) v = (float)c2;
                else if (lane == 2) v = (float)c3;
                else if (lane == 3) v = (float)c4;
                else if (lane == 4) v = (float)q;
                op[640 + lane] = v;
            }
        }
    }
}

extern "C" void kernel_launch(void* const* d_in, const int* in_sizes, int n_in,
                              void* d_out, int out_size, void* d_ws, size_t ws_size,
                              hipStream_t stream) {
    const int* src = (const int*)d_in[0];
    float* out = (float*)d_out;
    u64* P  = (u64*)d_ws;          // 16384 u64
    u64* SH = P + 16384;           // 65536 u64 (4 tables x 8 batch)
    int* sT = (int*)(P + 81920);   // 16384 int

    build_kernel<<<dim3(NBLK, BATCH), 64, 0, stream>>>(src, P, SH, sT);
    // 512 pair-tasks per b / 4 waves per WG -> grid (128, 8)
    compute_kernel<<<dim3(128, BATCH), 256, 0, stream>>>(P, SH, sT, out);
}

// Round 7
// 87.509 us; speedup vs baseline: 1.2025x; 1.2025x over previous
//
#include <hip/hip_runtime.h>

typedef unsigned long long u64;

#define S_LEN 2048
#define BATCH 8
#define NTOK 64
#define DMODEL 648
#define NBLK 32   // 32 blocks of 64 positions

// Workspace layout (u64 units):
//   P  [BATCH][2048]  @ 0     : bit jj of P[b][w*64+t] = (src[64w+jj] == t)
//   SH [BATCH][8192]  @ 16384 : per b, two interleaved table pairs:
//       SH[b][2*(w*64+t)+0]      = S1 row (src[64w+jj-1]==t)
//       SH[b][2*(w*64+t)+1]      = S2 row (src[64w+jj-2]==t)
//       SH[b][4096+2*(w*64+t)+0] = S3 row (src[64w+jj-3]==t)
//       SH[b][4096+2*(w*64+t)+1] = S4 row (src[64w+jj-4]==t)
//   sT [BATCH][S_LEN] @ 81920 : transposed src column (int)

__global__ __launch_bounds__(64) void build_kernel(const int* __restrict__ src,
                                                   u64* __restrict__ P,
                                                   u64* __restrict__ SH,
                                                   int* __restrict__ sT) {
    const int w = blockIdx.x, b = blockIdx.y;
    const int lane = threadIdx.x;
    const int p = (w << 6) + lane;
    const int tok  = src[p * BATCH + b];
    const int tokp = (w > 0) ? src[(p - 64) * BATCH + b] : -1;  // prev block
    u64 m_sel = 0, mp_sel = 0;
    #pragma unroll 8
    for (int t = 0; t < NTOK; ++t) {
        const u64 m  = __ballot(tok == t);
        const u64 mp = __ballot(tokp == t);
        if (lane == t) { m_sel = m; mp_sel = mp; }
    }
    const int idx = (w << 6) + lane;        // lane == token slot
    P[b * 2048 + idx] = m_sel;
    u64* S = SH + (size_t)b * 8192;
    S[2 * idx]            = (m_sel << 1) | (mp_sel >> 63);  // S1
    S[2 * idx + 1]        = (m_sel << 2) | (mp_sel >> 62);  // S2
    S[4096 + 2 * idx]     = (m_sel << 3) | (mp_sel >> 61);  // S3
    S[4096 + 2 * idx + 1] = (m_sel << 4) | (mp_sel >> 60);  // S4
    sT[b * S_LEN + p] = tok;
}

// ---------------------------------------------------------------------------
// Compute: WG = 256 threads = 4 waves; 64 KiB LDS -> exactly 2 WG/CU, 512 WGs
// -> all resident in one round. Wave o (0..255 per b) handles quartets o and
// 511-o (4 q each) -> ~32 balanced block-iters per wave. Lane = token id.
// Per block-iter, per r in 0..3 (q = q0+r), with tk[i] = s[q0-4+i]:
//   c = b128 C12[tk[4+r]] : c.x = S1 row (depth1, this r); c.y = S2 row
//       (depth2 row for r+1, since depth2 uses s[q-1] = tk[3+(r+1)])
//   d = b128 C34[tk[2+r]] : d.x = S3 row (depth3, this r); d.y = S4 row
//       (depth4 row for r+1, since depth4 uses s[q-3] = tk[1+(r+1)])
//   A1 = c.x & pv; A2 = A1 & pc.y; A3 = A2 & d.x; A4 = A3 & pd.y
//   h_i[lane] += popc(A_i);  c_i = wave-sum h_i (epilogue shfl reduce).
// 10 uniform b128 LDS reads per iter; pv = P[w][lane] prefetched from global.
// ---------------------------------------------------------------------------
__global__ __launch_bounds__(256, 2) void compute_kernel(const u64* __restrict__ P,
                                                         const u64* __restrict__ SH,
                                                         const int* __restrict__ sT,
                                                         float* __restrict__ out) {
    __shared__ __align__(16) u64 C12[4096];   // 32 KiB {S1,S2} interleaved
    __shared__ __align__(16) u64 C34[4096];   // 32 KiB {S3,S4} interleaved

    const int b = blockIdx.y;
    const int tid = threadIdx.x;
    const int lane = tid & 63;
    const int wv = tid >> 6;

    {   // stage tables (2 x 32 KiB contiguous, 16B vector copies)
        const ulonglong2* G = (const ulonglong2*)(SH + (size_t)b * 8192);
        ulonglong2* L1 = (ulonglong2*)C12;
        ulonglong2* L2 = (ulonglong2*)C34;
        #pragma unroll
        for (int i = tid; i < 2048; i += 256) L1[i] = G[i];
        #pragma unroll
        for (int i = tid; i < 2048; i += 256) L2[i] = G[2048 + i];
    }
    __syncthreads();

    const int o = blockIdx.x * 4 + wv;    // 0..255 per b
    const int* s = sT + b * S_LEN;
    const u64* Pb = P + (size_t)b * 2048;

    #pragma unroll 1
    for (int half = 0; half < 2; ++half) {
        const int quart = half ? (511 - o) : o;   // 0..511, balanced pairing
        const int q0 = quart << 2;                // 0..2044

        int tk[8];
        #pragma unroll
        for (int i = 0; i < 8; ++i) {
            const int idx = q0 - 4 + i;
            tk[i] = (idx >= 0) ? s[idx] : 0;   // clamp: provably-dead rows
        }

        int h1[4] = {}, h2[4] = {}, h3[4] = {}, h4[4] = {};
        int cuP[4];
        int cuF = 0;
        const int wq = q0 >> 6, rem0 = q0 & 63;

        u64 pv = Pb[lane];   // block 0 per-lane token mask
        for (int w = 0; w < wq; ++w) {
            const u64 pvn = Pb[((w + 1) << 6) + lane];  // prefetch next block
            cuF += __popcll(pv);
            const int wb = w << 7;   // interleaved-table index base (w*128)
            ulonglong2 pc = *(const ulonglong2*)&C12[wb + 2 * tk[3]];
            ulonglong2 pd = *(const ulonglong2*)&C34[wb + 2 * tk[1]];
            #pragma unroll
            for (int r = 0; r < 4; ++r) {
                const ulonglong2 c = *(const ulonglong2*)&C12[wb + 2 * tk[4 + r]];
                const ulonglong2 d = *(const ulonglong2*)&C34[wb + 2 * tk[2 + r]];
                const u64 A1 = c.x & pv;
                const u64 A2 = A1 & pc.y;
                const u64 A3 = A2 & d.x;
                const u64 A4 = A3 & pd.y;
                h1[r] += __popcll(A1);
                h2[r] += __popcll(A2);
                h3[r] += __popcll(A3);
                h4[r] += __popcll(A4);
                pc = c; pd = d;
            }
            pv = pvn;
        }

        {   // partial block w = wq: j-bits jj < rem0 + r
            const int wb = wq << 7;
            ulonglong2 pc = *(const ulonglong2*)&C12[wb + 2 * tk[3]];
            ulonglong2 pd = *(const ulonglong2*)&C34[wb + 2 * tk[1]];
            #pragma unroll
            for (int r = 0; r < 4; ++r) {
                const int rem = rem0 + r;                  // <= 63 always
                const u64 valid = (1ull << rem) - 1ull;    // rem==0 -> 0
                const u64 pvv = pv & valid;
                cuP[r] = cuF + __popcll(pvv);
                const ulonglong2 c = *(const ulonglong2*)&C12[wb + 2 * tk[4 + r]];
                const ulonglong2 d = *(const ulonglong2*)&C34[wb + 2 * tk[2 + r]];
                const u64 A1 = c.x & pvv;
                const u64 A2 = A1 & pc.y;
                const u64 A3 = A2 & d.x;
                const u64 A4 = A3 & pd.y;
                h1[r] += __popcll(A1);
                h2[r] += __popcll(A2);
                h3[r] += __popcll(A3);
                h4[r] += __popcll(A4);
                pc = c; pd = d;
            }
        }

        // Epilogue: c_i = wave-sum of h_i (packed 2x16-bit), write 648 chans.
        #pragma unroll
        for (int r = 0; r < 4; ++r) {
            const int q = q0 + r;
            int p01 = h1[r] | (h2[r] << 16);
            int p23 = h3[r] | (h4[r] << 16);
            #pragma unroll
            for (int sft = 1; sft < 64; sft <<= 1) {
                p01 += __shfl_xor(p01, sft);
                p23 += __shfl_xor(p23, sft);
            }
            const int c1 = p01 & 0xffff, c2 = p01 >> 16;
            const int c3 = p23 & 0xffff, c4 = p23 >> 16;

            float* op = out + ((size_t)q * BATCH + b) * DMODEL;
            #pragma unroll
            for (int m = 0; m <= 4; ++m) {   // one-hot blocks, sentinel -> 0
                const bool sent = (q - m) < 0;
                op[m * 64 + lane] = (!sent && lane == tk[4 + r - m]) ? 1.f : 0.f;
            }
            op[320 + lane] = (float)h1[r] / (float)(c1 ? c1 : 1);
            op[384 + lane] = (float)h2[r] / (float)(c2 ? c2 : 1);
            op[448 + lane] = (float)h3[r] / (float)(c3 ? c3 : 1);
            op[512 + lane] = (float)h4[r] / (float)(c4 ? c4 : 1);
            op[576 + lane] = (float)cuP[r] / (float)(q ? q : 1);
            if (lane < 8) {
                float v = 0.f;
                if (lane == 0) v = (float)c1;
                else if (lane == 1) v = (float)c2;
                else if (lane == 2) v = (float)c3;
                else if (lane == 3) v = (float)c4;
                else if (lane == 4) v = (float)q;
                op[640 + lane] = v;
            }
        }
    }
}

extern "C" void kernel_launch(void* const* d_in, const int* in_sizes, int n_in,
                              void* d_out, int out_size, void* d_ws, size_t ws_size,
                              hipStream_t stream) {
    const int* src = (const int*)d_in[0];
    float* out = (float*)d_out;
    u64* P  = (u64*)d_ws;          // 16384 u64
    u64* SH = P + 16384;           // 65536 u64 (8 b x 8192)
    int* sT = (int*)(P + 81920);   // 16384 int

    build_kernel<<<dim3(NBLK, BATCH), 64, 0, stream>>>(src, P, SH, sT);
    // 256 wave-tasks per b / 4 waves per WG -> grid (64, 8) = 512 WGs (2/CU)
    compute_kernel<<<dim3(64, BATCH), 256, 0, stream>>>(P, SH, sT, out);
}